// Round 1
// baseline (510.342 us; speedup 1.0000x reference)
//
#include <hip/hip_runtime.h>
#include <stdint.h>

#define NT 16384   // tokens = 32*512
#define SDIM 512
#define NE 8
#define BM 128
#define BN 128
#define BK 32
#define MAX_TILES 264

typedef __attribute__((ext_vector_type(8))) short short8v;
typedef __attribute__((ext_vector_type(8))) unsigned short ushort8v;
typedef __attribute__((ext_vector_type(4))) float f32x4;

#define GLOAD_LDS16(gp, lp) __builtin_amdgcn_global_load_lds( \
    (const __attribute__((address_space(1))) uint32_t*)(gp), \
    (__attribute__((address_space(3))) uint32_t*)(lp), 16, 0, 0)

__device__ __forceinline__ unsigned short f2bf(float f) {
  uint32_t x = __float_as_uint(f);
  x = (x + 0x7FFFu + ((x >> 16) & 1u)) >> 16;
  return (unsigned short)x;
}

// ---------------- expert_w fp32 -> bf16 ----------------
__global__ __launch_bounds__(256) void convw_kernel(const float* __restrict__ w,
                                                    unsigned short* __restrict__ wb) {
  int i = (blockIdx.x * 256 + threadIdx.x) * 8;
  const float4* p = (const float4*)(w + i);
  float4 a = p[0], b = p[1];
  ushort8v u;
  u[0] = f2bf(a.x); u[1] = f2bf(a.y); u[2] = f2bf(a.z); u[3] = f2bf(a.w);
  u[4] = f2bf(b.x); u[5] = f2bf(b.y); u[6] = f2bf(b.z); u[7] = f2bf(b.w);
  *(ushort8v*)(wb + i) = u;
}

// ---------------- gating: fp64 logits, softmax, top-2, x->bf16 ----------------
__global__ __launch_bounds__(256) void gate_kernel(
    const float* __restrict__ x, const float* __restrict__ gw,
    unsigned short* __restrict__ xb, float* __restrict__ gates_out,
    float* __restrict__ wts, int* __restrict__ sels,
    int* __restrict__ cnt, int* __restrict__ list) {
  int lane = threadIdx.x & 63;
  int wv = threadIdx.x >> 6;
  int t = blockIdx.x * 4 + wv;
  const float* xr = x + (size_t)t * SDIM;
  float4 xa = ((const float4*)xr)[lane * 2];
  float4 xbv = ((const float4*)xr)[lane * 2 + 1];

  // bf16 copy of x row
  ushort8v u;
  u[0] = f2bf(xa.x); u[1] = f2bf(xa.y); u[2] = f2bf(xa.z); u[3] = f2bf(xa.w);
  u[4] = f2bf(xbv.x); u[5] = f2bf(xbv.y); u[6] = f2bf(xbv.z); u[7] = f2bf(xbv.w);
  *(ushort8v*)(xb + (size_t)t * SDIM + lane * 8) = u;

  double part[NE];
#pragma unroll
  for (int e = 0; e < NE; e++) {
    const float4* g4 = (const float4*)(gw + e * SDIM + lane * 8);
    float4 ga = g4[0], gb = g4[1];
    double s;
    s  = (double)xa.x * ga.x;  s += (double)xa.y * ga.y;
    s += (double)xa.z * ga.z;  s += (double)xa.w * ga.w;
    s += (double)xbv.x * gb.x; s += (double)xbv.y * gb.y;
    s += (double)xbv.z * gb.z; s += (double)xbv.w * gb.w;
    part[e] = s;
  }
#pragma unroll
  for (int e = 0; e < NE; e++) {
#pragma unroll
    for (int off = 32; off >= 1; off >>= 1)
      part[e] += __shfl_xor(part[e], off, 64);
  }

  float lg[NE];
#pragma unroll
  for (int e = 0; e < NE; e++) lg[e] = (float)part[e];
  float mx = lg[0];
#pragma unroll
  for (int e = 1; e < NE; e++) mx = fmaxf(mx, lg[e]);
  float ex[NE]; float sum = 0.f;
#pragma unroll
  for (int e = 0; e < NE; e++) { ex[e] = expf(lg[e] - mx); sum += ex[e]; }
  float inv = 1.0f / sum;
  float g[NE];
#pragma unroll
  for (int e = 0; e < NE; e++) g[e] = ex[e] * inv;

  // top-2, stable (lower index wins ties) to match jax.lax.top_k
  int s0 = 0; float v0 = g[0];
#pragma unroll
  for (int e = 1; e < NE; e++) if (g[e] > v0) { v0 = g[e]; s0 = e; }
  int s1 = -1; float v1 = -1.0f;
#pragma unroll
  for (int e = 0; e < NE; e++) if (e != s0 && g[e] > v1) { v1 = g[e]; s1 = e; }

  if (lane == 0) {
    float* go = gates_out + (size_t)t * NE;
#pragma unroll
    for (int e = 0; e < NE; e++) go[e] = g[e];
    wts[t * 2] = v0; wts[t * 2 + 1] = v1;
    sels[t * 2] = s0; sels[t * 2 + 1] = s1;
    int p0 = atomicAdd(cnt + s0, 1);
    list[s0 * NT + p0] = t * 2;
    int p1 = atomicAdd(cnt + s1, 1);
    list[s1 * NT + p1] = t * 2 + 1;
  }
}

// ---------------- tile descriptors ----------------
__global__ void build_tiles(const int* __restrict__ cnt, int4* __restrict__ desc) {
  if (threadIdx.x == 0 && blockIdx.x == 0) {
    int n = 0;
    for (int e = 0; e < NE; e++) {
      int c = cnt[e];
      for (int s = 0; s < c; s += BM) {
        desc[n++] = make_int4(e, s, min(BM, c - s), 0);
      }
    }
    for (; n < MAX_TILES; n++) desc[n] = make_int4(0, 0, 0, 0);
  }
}

// ---------------- grouped GEMM: gathered tokens x expert weights ----------------
__global__ __launch_bounds__(256, 2) void moe_gemm(
    const unsigned short* __restrict__ xb, const unsigned short* __restrict__ wb,
    const int* __restrict__ list, const float* __restrict__ wts,
    const int4* __restrict__ desc, float* __restrict__ out) {
  int4 d = desc[blockIdx.x];
  int rows = d.z;
  if (rows == 0) return;
  int e = d.x, start = d.y;
  int nbase = blockIdx.y * BN;
  const int* gl = list + e * NT + start;

  __shared__ unsigned short lA[BM * BK];
  __shared__ unsigned short lB[BM * BK];

  int tid = threadIdx.x, lane = tid & 63, wv = tid >> 6;
  // staging: chunk c covers row c>>2, 8-elem group c&3 (16B per lane)
  int c0 = wv * 64 + lane;
  int c1 = 256 + c0;
  int r0 = c0 >> 2, r1 = c1 >> 2;
  int q0 = (c0 & 3) * 8, q1 = (c1 & 3) * 8;
  int t0r = (r0 < rows) ? (gl[r0] >> 1) : (gl[0] >> 1);
  int t1r = (r1 < rows) ? (gl[r1] >> 1) : (gl[0] >> 1);
  const unsigned short* ga0 = xb + (size_t)t0r * SDIM + q0;
  const unsigned short* ga1 = xb + (size_t)t1r * SDIM + q1;
  const unsigned short* gb0 = wb + (size_t)(e * SDIM + nbase + r0) * SDIM + q0;
  const unsigned short* gb1 = wb + (size_t)(e * SDIM + nbase + r1) * SDIM + q1;

  char* lAb = (char*)lA; char* lBb = (char*)lB;
  int wr = wv >> 1, wc = wv & 1;
  int arow = wr * 64 + (lane & 15);
  int brow = wc * 64 + (lane & 15);
  int kof = (lane >> 4) * 8;

  f32x4 acc[4][4];
#pragma unroll
  for (int i = 0; i < 4; i++)
#pragma unroll
    for (int j = 0; j < 4; j++) acc[i][j] = (f32x4){0.f, 0.f, 0.f, 0.f};

  for (int k0 = 0; k0 < SDIM; k0 += BK) {
    GLOAD_LDS16(ga0 + k0, lAb + wv * 1024);
    GLOAD_LDS16(ga1 + k0, lAb + 4096 + wv * 1024);
    GLOAD_LDS16(gb0 + k0, lBb + wv * 1024);
    GLOAD_LDS16(gb1 + k0, lBb + 4096 + wv * 1024);
    __syncthreads();
    short8v a[4], b[4];
#pragma unroll
    for (int mi = 0; mi < 4; mi++) a[mi] = *(const short8v*)&lA[(arow + mi * 16) * BK + kof];
#pragma unroll
    for (int ni = 0; ni < 4; ni++) b[ni] = *(const short8v*)&lB[(brow + ni * 16) * BK + kof];
#pragma unroll
    for (int mi = 0; mi < 4; mi++)
#pragma unroll
      for (int ni = 0; ni < 4; ni++)
        acc[mi][ni] = __builtin_amdgcn_mfma_f32_16x16x32_bf16(a[mi], b[ni], acc[mi][ni], 0, 0, 0);
    __syncthreads();
  }

  // epilogue: scatter weighted rows (2 commutative atomic adds per out element total)
  int rg = lane >> 4;
  int ncol = nbase + wc * 64 + (lane & 15);
#pragma unroll
  for (int mi = 0; mi < 4; mi++) {
#pragma unroll
    for (int r = 0; r < 4; r++) {
      int m = wr * 64 + mi * 16 + rg * 4 + r;
      if (m < rows) {
        int entry = gl[m];
        int tok = entry >> 1, slot = entry & 1;
        float wgt = wts[tok * 2 + slot];
        float* orow = out + (size_t)tok * SDIM + ncol;
#pragma unroll
        for (int ni = 0; ni < 4; ni++)
          atomicAdd(orow + ni * 16, acc[mi][ni][r] * wgt);
      }
    }
  }
}

// ---------------- bias + relu ----------------
__global__ __launch_bounds__(256) void bias_relu(
    float* __restrict__ out, const float* __restrict__ eb,
    const int* __restrict__ sels, const float* __restrict__ wts) {
  int t = blockIdx.x;
  int s0 = sels[t * 2], s1 = sels[t * 2 + 1];
  float w0 = wts[t * 2], w1 = wts[t * 2 + 1];
  int o = threadIdx.x * 2;
  float* op = out + (size_t)t * SDIM + o;
  float2 v = *(float2*)op;
  float2 b0 = *(const float2*)(eb + s0 * SDIM + o);
  float2 b1 = *(const float2*)(eb + s1 * SDIM + o);
  v.x = fmaxf(v.x + w0 * b0.x + w1 * b1.x, 0.f);
  v.y = fmaxf(v.y + w0 * b0.y + w1 * b1.y, 0.f);
  *(float2*)op = v;
}

extern "C" void kernel_launch(void* const* d_in, const int* in_sizes, int n_in,
                              void* d_out, int out_size, void* d_ws, size_t ws_size,
                              hipStream_t stream) {
  const float* x        = (const float*)d_in[0];
  const float* gate_w   = (const float*)d_in[1];
  const float* expert_w = (const float*)d_in[2];
  const float* expert_b = (const float*)d_in[3];
  float* out = (float*)d_out;

  char* ws = (char*)d_ws;
  unsigned short* xb = (unsigned short*)(ws);                 // 16,777,216 B
  unsigned short* wb = (unsigned short*)(ws + 16777216);      //  4,194,304 B
  float* wts = (float*)(ws + 20971520);                       //    131,072 B
  int* sels  = (int*)(ws + 21102592);                         //    131,072 B
  int* cnt   = (int*)(ws + 21233664);                         //         64 B
  int* list  = (int*)(ws + 21233728);                         //    524,288 B
  int4* desc = (int4*)(ws + 21758016);                        //      4,224 B

  hipMemsetAsync(out, 0, (size_t)NT * SDIM * sizeof(float), stream);
  hipMemsetAsync(cnt, 0, 64, stream);

  convw_kernel<<<1024, 256, 0, stream>>>(expert_w, wb);
  gate_kernel<<<NT / 4, 256, 0, stream>>>(x, gate_w, xb, out + (size_t)NT * SDIM,
                                          wts, sels, cnt, list);
  build_tiles<<<1, 64, 0, stream>>>(cnt, desc);
  dim3 gg(MAX_TILES, SDIM / BN);
  moe_gemm<<<gg, 256, 0, stream>>>(xb, wb, list, wts, desc, out);
  bias_relu<<<NT, 256, 0, stream>>>(out, expert_b, sels, wts);
}

// Round 2
// 155.635 us; speedup vs baseline: 3.2791x; 3.2791x over previous
//
#include <hip/hip_runtime.h>
#include <stdint.h>

#define NT 16384   // tokens = 32*512
#define SDIM 512
#define NE 8
#define BM 128
#define BN 128
#define BK 32
#define MAX_TILES 264

typedef __attribute__((ext_vector_type(8))) short short8v;
typedef __attribute__((ext_vector_type(8))) unsigned short ushort8v;
typedef __attribute__((ext_vector_type(4))) float f32x4;

#define GLOAD_LDS16(gp, lp) __builtin_amdgcn_global_load_lds( \
    (const __attribute__((address_space(1))) uint32_t*)(gp), \
    (__attribute__((address_space(3))) uint32_t*)(lp), 16, 0, 0)

__device__ __forceinline__ unsigned short f2bf(float f) {
  uint32_t x = __float_as_uint(f);
  x = (x + 0x7FFFu + ((x >> 16) & 1u)) >> 16;
  return (unsigned short)x;
}

// ---------------- expert_w fp32 -> bf16 ----------------
__global__ __launch_bounds__(256) void convw_kernel(const float* __restrict__ w,
                                                    unsigned short* __restrict__ wb) {
  int i = (blockIdx.x * 256 + threadIdx.x) * 8;
  const float4* p = (const float4*)(w + i);
  float4 a = p[0], b = p[1];
  ushort8v u;
  u[0] = f2bf(a.x); u[1] = f2bf(a.y); u[2] = f2bf(a.z); u[3] = f2bf(a.w);
  u[4] = f2bf(b.x); u[5] = f2bf(b.y); u[6] = f2bf(b.z); u[7] = f2bf(b.w);
  *(ushort8v*)(wb + i) = u;
}

// ---------------- gating: fp64 logits, softmax, top-2, x->bf16 (NO global atomics) ----------------
__global__ __launch_bounds__(256) void gate_kernel(
    const float* __restrict__ x, const float* __restrict__ gw,
    unsigned short* __restrict__ xb, float* __restrict__ gates_out,
    float* __restrict__ wts, int* __restrict__ sels) {
  int lane = threadIdx.x & 63;
  int wv = threadIdx.x >> 6;
  int t = blockIdx.x * 4 + wv;
  const float* xr = x + (size_t)t * SDIM;
  float4 xa = ((const float4*)xr)[lane * 2];
  float4 xbv = ((const float4*)xr)[lane * 2 + 1];

  // bf16 copy of x row
  ushort8v u;
  u[0] = f2bf(xa.x); u[1] = f2bf(xa.y); u[2] = f2bf(xa.z); u[3] = f2bf(xa.w);
  u[4] = f2bf(xbv.x); u[5] = f2bf(xbv.y); u[6] = f2bf(xbv.z); u[7] = f2bf(xbv.w);
  *(ushort8v*)(xb + (size_t)t * SDIM + lane * 8) = u;

  double part[NE];
#pragma unroll
  for (int e = 0; e < NE; e++) {
    const float4* g4 = (const float4*)(gw + e * SDIM + lane * 8);
    float4 ga = g4[0], gb = g4[1];
    double s;
    s  = (double)xa.x * ga.x;  s += (double)xa.y * ga.y;
    s += (double)xa.z * ga.z;  s += (double)xa.w * ga.w;
    s += (double)xbv.x * gb.x; s += (double)xbv.y * gb.y;
    s += (double)xbv.z * gb.z; s += (double)xbv.w * gb.w;
    part[e] = s;
  }
#pragma unroll
  for (int e = 0; e < NE; e++) {
#pragma unroll
    for (int off = 32; off >= 1; off >>= 1)
      part[e] += __shfl_xor(part[e], off, 64);
  }

  float lg[NE];
#pragma unroll
  for (int e = 0; e < NE; e++) lg[e] = (float)part[e];
  float mx = lg[0];
#pragma unroll
  for (int e = 1; e < NE; e++) mx = fmaxf(mx, lg[e]);
  float ex[NE]; float sum = 0.f;
#pragma unroll
  for (int e = 0; e < NE; e++) { ex[e] = expf(lg[e] - mx); sum += ex[e]; }
  float inv = 1.0f / sum;
  float g[NE];
#pragma unroll
  for (int e = 0; e < NE; e++) g[e] = ex[e] * inv;

  // top-2, stable (lower index wins ties) to match jax.lax.top_k
  int s0 = 0; float v0 = g[0];
#pragma unroll
  for (int e = 1; e < NE; e++) if (g[e] > v0) { v0 = g[e]; s0 = e; }
  int s1 = -1; float v1 = -1.0f;
#pragma unroll
  for (int e = 0; e < NE; e++) if (e != s0 && g[e] > v1) { v1 = g[e]; s1 = e; }

  if (lane == 0) {
    float* go = gates_out + (size_t)t * NE;
#pragma unroll
    for (int e = 0; e < NE; e++) go[e] = g[e];
    wts[t * 2] = v0; wts[t * 2 + 1] = v1;
    sels[t * 2] = s0; sels[t * 2 + 1] = s1;
  }
}

// ---------------- block-aggregated scatter: build per-expert token lists ----------------
__global__ __launch_bounds__(1024) void scatter_kernel(
    const int* __restrict__ sels, int* __restrict__ cnt, int* __restrict__ list) {
  __shared__ int lcnt[NE];
  __shared__ int lbase[NE];
  int tid = threadIdx.x;
  if (tid < NE) lcnt[tid] = 0;
  __syncthreads();
  int t = blockIdx.x * 1024 + tid;
  int s0 = sels[t * 2], s1 = sels[t * 2 + 1];
  int p0 = atomicAdd(&lcnt[s0], 1);
  int p1 = atomicAdd(&lcnt[s1], 1);
  __syncthreads();
  if (tid < NE) lbase[tid] = atomicAdd(cnt + tid, lcnt[tid]);
  __syncthreads();
  list[s0 * NT + lbase[s0] + p0] = t * 2;
  list[s1 * NT + lbase[s1] + p1] = t * 2 + 1;
}

// ---------------- tile descriptors ----------------
__global__ void build_tiles(const int* __restrict__ cnt, int4* __restrict__ desc) {
  if (threadIdx.x == 0 && blockIdx.x == 0) {
    int n = 0;
    for (int e = 0; e < NE; e++) {
      int c = cnt[e];
      for (int s = 0; s < c; s += BM) {
        desc[n++] = make_int4(e, s, min(BM, c - s), 0);
      }
    }
    for (; n < MAX_TILES; n++) desc[n] = make_int4(0, 0, 0, 0);
  }
}

// ---------------- grouped GEMM: gathered tokens x expert weights ----------------
__global__ __launch_bounds__(256, 2) void moe_gemm(
    const unsigned short* __restrict__ xb, const unsigned short* __restrict__ wb,
    const int* __restrict__ list, const float* __restrict__ wts,
    const int4* __restrict__ desc, float* __restrict__ out) {
  int4 d = desc[blockIdx.x];
  int rows = d.z;
  if (rows == 0) return;
  int e = d.x, start = d.y;
  int nbase = blockIdx.y * BN;
  const int* gl = list + e * NT + start;

  __shared__ unsigned short lA[BM * BK];
  __shared__ unsigned short lB[BM * BK];

  int tid = threadIdx.x, lane = tid & 63, wv = tid >> 6;
  // staging: chunk c covers row c>>2, 8-elem group c&3 (16B per lane)
  int c0 = wv * 64 + lane;
  int c1 = 256 + c0;
  int r0 = c0 >> 2, r1 = c1 >> 2;
  int q0 = (c0 & 3) * 8, q1 = (c1 & 3) * 8;
  int t0r = (r0 < rows) ? (gl[r0] >> 1) : (gl[0] >> 1);
  int t1r = (r1 < rows) ? (gl[r1] >> 1) : (gl[0] >> 1);
  const unsigned short* ga0 = xb + (size_t)t0r * SDIM + q0;
  const unsigned short* ga1 = xb + (size_t)t1r * SDIM + q1;
  const unsigned short* gb0 = wb + (size_t)(e * SDIM + nbase + r0) * SDIM + q0;
  const unsigned short* gb1 = wb + (size_t)(e * SDIM + nbase + r1) * SDIM + q1;

  char* lAb = (char*)lA; char* lBb = (char*)lB;
  int wr = wv >> 1, wc = wv & 1;
  int arow = wr * 64 + (lane & 15);
  int brow = wc * 64 + (lane & 15);
  int kof = (lane >> 4) * 8;

  f32x4 acc[4][4];
#pragma unroll
  for (int i = 0; i < 4; i++)
#pragma unroll
    for (int j = 0; j < 4; j++) acc[i][j] = (f32x4){0.f, 0.f, 0.f, 0.f};

  for (int k0 = 0; k0 < SDIM; k0 += BK) {
    GLOAD_LDS16(ga0 + k0, lAb + wv * 1024);
    GLOAD_LDS16(ga1 + k0, lAb + 4096 + wv * 1024);
    GLOAD_LDS16(gb0 + k0, lBb + wv * 1024);
    GLOAD_LDS16(gb1 + k0, lBb + 4096 + wv * 1024);
    __syncthreads();
    short8v a[4], b[4];
#pragma unroll
    for (int mi = 0; mi < 4; mi++) a[mi] = *(const short8v*)&lA[(arow + mi * 16) * BK + kof];
#pragma unroll
    for (int ni = 0; ni < 4; ni++) b[ni] = *(const short8v*)&lB[(brow + ni * 16) * BK + kof];
#pragma unroll
    for (int mi = 0; mi < 4; mi++)
#pragma unroll
      for (int ni = 0; ni < 4; ni++)
        acc[mi][ni] = __builtin_amdgcn_mfma_f32_16x16x32_bf16(a[mi], b[ni], acc[mi][ni], 0, 0, 0);
    __syncthreads();
  }

  // epilogue: scatter weighted rows (2 commutative atomic adds per out element total)
  int rg = lane >> 4;
  int ncol = nbase + wc * 64 + (lane & 15);
#pragma unroll
  for (int mi = 0; mi < 4; mi++) {
#pragma unroll
    for (int r = 0; r < 4; r++) {
      int m = wr * 64 + mi * 16 + rg * 4 + r;
      if (m < rows) {
        int entry = gl[m];
        int tok = entry >> 1, slot = entry & 1;
        float wgt = wts[tok * 2 + slot];
        float* orow = out + (size_t)tok * SDIM + ncol;
#pragma unroll
        for (int ni = 0; ni < 4; ni++)
          atomicAdd(orow + ni * 16, acc[mi][ni][r] * wgt);
      }
    }
  }
}

// ---------------- bias + relu ----------------
__global__ __launch_bounds__(256) void bias_relu(
    float* __restrict__ out, const float* __restrict__ eb,
    const int* __restrict__ sels, const float* __restrict__ wts) {
  int t = blockIdx.x;
  int s0 = sels[t * 2], s1 = sels[t * 2 + 1];
  float w0 = wts[t * 2], w1 = wts[t * 2 + 1];
  int o = threadIdx.x * 2;
  float* op = out + (size_t)t * SDIM + o;
  float2 v = *(float2*)op;
  float2 b0 = *(const float2*)(eb + s0 * SDIM + o);
  float2 b1 = *(const float2*)(eb + s1 * SDIM + o);
  v.x = fmaxf(v.x + w0 * b0.x + w1 * b1.x, 0.f);
  v.y = fmaxf(v.y + w0 * b0.y + w1 * b1.y, 0.f);
  *(float2*)op = v;
}

extern "C" void kernel_launch(void* const* d_in, const int* in_sizes, int n_in,
                              void* d_out, int out_size, void* d_ws, size_t ws_size,
                              hipStream_t stream) {
  const float* x        = (const float*)d_in[0];
  const float* gate_w   = (const float*)d_in[1];
  const float* expert_w = (const float*)d_in[2];
  const float* expert_b = (const float*)d_in[3];
  float* out = (float*)d_out;

  char* ws = (char*)d_ws;
  unsigned short* xb = (unsigned short*)(ws);                 // 16,777,216 B
  unsigned short* wb = (unsigned short*)(ws + 16777216);      //  4,194,304 B
  float* wts = (float*)(ws + 20971520);                       //    131,072 B
  int* sels  = (int*)(ws + 21102592);                         //    131,072 B
  int* cnt   = (int*)(ws + 21233664);                         //         64 B
  int* list  = (int*)(ws + 21233728);                         //    524,288 B
  int4* desc = (int4*)(ws + 21758016);                        //      4,224 B

  hipMemsetAsync(out, 0, (size_t)NT * SDIM * sizeof(float), stream);
  hipMemsetAsync(cnt, 0, 64, stream);

  convw_kernel<<<1024, 256, 0, stream>>>(expert_w, wb);
  gate_kernel<<<NT / 4, 256, 0, stream>>>(x, gate_w, xb, out + (size_t)NT * SDIM,
                                          wts, sels);
  scatter_kernel<<<NT / 1024, 1024, 0, stream>>>(sels, cnt, list);
  build_tiles<<<1, 64, 0, stream>>>(cnt, desc);
  dim3 gg(MAX_TILES, SDIM / BN);
  moe_gemm<<<gg, 256, 0, stream>>>(xb, wb, list, wts, desc, out);
  bias_relu<<<NT, 256, 0, stream>>>(out, expert_b, sels, wts);
}

// Round 3
// 115.017 us; speedup vs baseline: 4.4371x; 1.3531x over previous
//
#include <hip/hip_runtime.h>
#include <stdint.h>

#define NT 16384   // tokens = 32*512
#define SDIM 512
#define NE 8
#define BM 128
#define BN 128
#define BK 32
#define MAX_TP 136   // max tiles per pass: ceil-sum over experts <= 128+7

typedef __attribute__((ext_vector_type(8))) short short8v;
typedef __attribute__((ext_vector_type(8))) unsigned short ushort8v;
typedef __attribute__((ext_vector_type(4))) float f32x4;

#define GLOAD_LDS16(gp, lp) __builtin_amdgcn_global_load_lds( \
    (const __attribute__((address_space(1))) uint32_t*)(gp), \
    (__attribute__((address_space(3))) uint32_t*)(lp), 16, 0, 0)

__device__ __forceinline__ unsigned short f2bf(float f) {
  uint32_t x = __float_as_uint(f);
  x = (x + 0x7FFFu + ((x >> 16) & 1u)) >> 16;
  return (unsigned short)x;
}

// ---------------- expert_w fp32 -> bf16 ----------------
__global__ __launch_bounds__(256) void convw_kernel(const float* __restrict__ w,
                                                    unsigned short* __restrict__ wb) {
  int i = (blockIdx.x * 256 + threadIdx.x) * 8;
  const float4* p = (const float4*)(w + i);
  float4 a = p[0], b = p[1];
  ushort8v u;
  u[0] = f2bf(a.x); u[1] = f2bf(a.y); u[2] = f2bf(a.z); u[3] = f2bf(a.w);
  u[4] = f2bf(b.x); u[5] = f2bf(b.y); u[6] = f2bf(b.z); u[7] = f2bf(b.w);
  *(ushort8v*)(wb + i) = u;
}

// ---------------- gating: fp64 logits, softmax, top-2, x->bf16 ----------------
__global__ __launch_bounds__(256) void gate_kernel(
    const float* __restrict__ x, const float* __restrict__ gw,
    unsigned short* __restrict__ xb, float* __restrict__ gates_out,
    float* __restrict__ wts, int* __restrict__ sels) {
  int lane = threadIdx.x & 63;
  int wv = threadIdx.x >> 6;
  int t = blockIdx.x * 4 + wv;
  const float* xr = x + (size_t)t * SDIM;
  float4 xa = ((const float4*)xr)[lane * 2];
  float4 xbv = ((const float4*)xr)[lane * 2 + 1];

  ushort8v u;
  u[0] = f2bf(xa.x); u[1] = f2bf(xa.y); u[2] = f2bf(xa.z); u[3] = f2bf(xa.w);
  u[4] = f2bf(xbv.x); u[5] = f2bf(xbv.y); u[6] = f2bf(xbv.z); u[7] = f2bf(xbv.w);
  *(ushort8v*)(xb + (size_t)t * SDIM + lane * 8) = u;

  double part[NE];
#pragma unroll
  for (int e = 0; e < NE; e++) {
    const float4* g4 = (const float4*)(gw + e * SDIM + lane * 8);
    float4 ga = g4[0], gb = g4[1];
    double s;
    s  = (double)xa.x * ga.x;  s += (double)xa.y * ga.y;
    s += (double)xa.z * ga.z;  s += (double)xa.w * ga.w;
    s += (double)xbv.x * gb.x; s += (double)xbv.y * gb.y;
    s += (double)xbv.z * gb.z; s += (double)xbv.w * gb.w;
    part[e] = s;
  }
#pragma unroll
  for (int e = 0; e < NE; e++) {
#pragma unroll
    for (int off = 32; off >= 1; off >>= 1)
      part[e] += __shfl_xor(part[e], off, 64);
  }

  float lg[NE];
#pragma unroll
  for (int e = 0; e < NE; e++) lg[e] = (float)part[e];
  float mx = lg[0];
#pragma unroll
  for (int e = 1; e < NE; e++) mx = fmaxf(mx, lg[e]);
  float ex[NE]; float sum = 0.f;
#pragma unroll
  for (int e = 0; e < NE; e++) { ex[e] = expf(lg[e] - mx); sum += ex[e]; }
  float inv = 1.0f / sum;
  float g[NE];
#pragma unroll
  for (int e = 0; e < NE; e++) g[e] = ex[e] * inv;

  // top-2, stable (lower index wins ties) to match jax.lax.top_k
  int s0 = 0; float v0 = g[0];
#pragma unroll
  for (int e = 1; e < NE; e++) if (g[e] > v0) { v0 = g[e]; s0 = e; }
  int s1 = -1; float v1 = -1.0f;
#pragma unroll
  for (int e = 0; e < NE; e++) if (e != s0 && g[e] > v1) { v1 = g[e]; s1 = e; }

  if (lane == 0) {
    float* go = gates_out + (size_t)t * NE;
#pragma unroll
    for (int e = 0; e < NE; e++) go[e] = g[e];
    wts[t * 2] = v0; wts[t * 2 + 1] = v1;
    sels[t * 2] = s0; sels[t * 2 + 1] = s1;
  }
}

// ---------------- block-aggregated scatter: per-slot per-expert token lists ----------------
__global__ __launch_bounds__(1024) void scatter_kernel(
    const int* __restrict__ sels, int* __restrict__ cnt,
    int* __restrict__ list0, int* __restrict__ list1) {
  __shared__ int lc[16];
  __shared__ int lb[16];
  int tid = threadIdx.x;
  if (tid < 16) lc[tid] = 0;
  __syncthreads();
  int t = blockIdx.x * 1024 + tid;
  int s0 = sels[t * 2], s1 = sels[t * 2 + 1];
  int p0 = atomicAdd(&lc[s0], 1);
  int p1 = atomicAdd(&lc[8 + s1], 1);
  __syncthreads();
  if (tid < 16) lb[tid] = atomicAdd(cnt + tid, lc[tid]);
  __syncthreads();
  list0[s0 * NT + lb[s0] + p0] = t;
  list1[s1 * NT + lb[8 + s1] + p1] = t;
}

// ---------------- tile descriptors (both passes) ----------------
__global__ void build_tiles(const int* __restrict__ cnt,
                            int4* __restrict__ desc0, int4* __restrict__ desc1) {
  int wv = threadIdx.x >> 6;
  int lane = threadIdx.x & 63;
  const int* c = cnt + wv * NE;
  int4* d = wv ? desc1 : desc0;
  if (lane == 0) {
    int n = 0;
    for (int e = 0; e < NE; e++) {
      int cc = c[e];
      for (int s = 0; s < cc; s += BM) d[n++] = make_int4(e, s, min(BM, cc - s), 0);
    }
    for (; n < MAX_TP; n++) d[n] = make_int4(0, 0, 0, 0);
  }
}

// ---------------- grouped GEMM pass (0: write, 1: accumulate+relu) ----------------
__global__ __launch_bounds__(256, 4) void moe_gemm(
    const unsigned short* __restrict__ xb, const unsigned short* __restrict__ wb,
    const int* __restrict__ list, const float* __restrict__ wts,
    const int4* __restrict__ desc, const float* __restrict__ eb,
    float* __restrict__ out, int pass) {
  int4 d = desc[blockIdx.x];
  int rows = d.z;
  if (rows == 0) return;
  int e = d.x, start = d.y;
  int nbase = blockIdx.y * BN;
  const int* gl = list + e * NT + start;

  __shared__ unsigned short lA[2][BM * BK];
  __shared__ unsigned short lB[2][BM * BK];

  int tid = threadIdx.x, lane = tid & 63, wv = tid >> 6;
  // staging: chunk c covers row c>>2, 8-elem group c&3 (16B per lane)
  int c0 = wv * 64 + lane;
  int c1 = 256 + c0;
  int r0 = c0 >> 2, r1 = c1 >> 2;
  int q0 = (c0 & 3) * 8, q1 = (c1 & 3) * 8;
  int t0r = (r0 < rows) ? gl[r0] : gl[0];
  int t1r = (r1 < rows) ? gl[r1] : gl[0];
  const unsigned short* ga0 = xb + (size_t)t0r * SDIM + q0;
  const unsigned short* ga1 = xb + (size_t)t1r * SDIM + q1;
  const unsigned short* gb0 = wb + (size_t)(e * SDIM + nbase + r0) * SDIM + q0;
  const unsigned short* gb1 = wb + (size_t)(e * SDIM + nbase + r1) * SDIM + q1;

  char* lAb = (char*)lA;
  char* lBb = (char*)lB;
  int wr = wv >> 1, wc = wv & 1;
  int arow = wr * 64 + (lane & 15);
  int brow = wc * 64 + (lane & 15);
  int kof = (lane >> 4) * 8;

  f32x4 acc[4][4];
#pragma unroll
  for (int i = 0; i < 4; i++)
#pragma unroll
    for (int j = 0; j < 4; j++) acc[i][j] = (f32x4){0.f, 0.f, 0.f, 0.f};

#define STAGE(buf, k0) do { \
    GLOAD_LDS16(ga0 + (k0), lAb + (buf) * 8192 + wv * 1024); \
    GLOAD_LDS16(ga1 + (k0), lAb + (buf) * 8192 + 4096 + wv * 1024); \
    GLOAD_LDS16(gb0 + (k0), lBb + (buf) * 8192 + wv * 1024); \
    GLOAD_LDS16(gb1 + (k0), lBb + (buf) * 8192 + 4096 + wv * 1024); \
  } while (0)

#define COMPUTE(buf) do { \
    const unsigned short* pA = lA[buf]; \
    const unsigned short* pB = lB[buf]; \
    short8v a[4], b[4]; \
    _Pragma("unroll") \
    for (int mi = 0; mi < 4; mi++) a[mi] = *(const short8v*)&pA[(arow + mi * 16) * BK + kof]; \
    _Pragma("unroll") \
    for (int ni = 0; ni < 4; ni++) b[ni] = *(const short8v*)&pB[(brow + ni * 16) * BK + kof]; \
    _Pragma("unroll") \
    for (int mi = 0; mi < 4; mi++) \
      _Pragma("unroll") \
      for (int ni = 0; ni < 4; ni++) \
        acc[mi][ni] = __builtin_amdgcn_mfma_f32_16x16x32_bf16(a[mi], b[ni], acc[mi][ni], 0, 0, 0); \
  } while (0)

  STAGE(0, 0);
  __syncthreads();
  int buf = 0;
#pragma unroll 1
  for (int t = 0; t < (SDIM / BK) - 1; t++) {
    STAGE(buf ^ 1, (t + 1) * BK);   // issue next tile loads
    COMPUTE(buf);                   // ds_read + MFMA current
    __syncthreads();                // drains vmcnt+lgkm, flips buffer safely
    buf ^= 1;
  }
  COMPUTE(buf);

  // epilogue: unique-writer stores; pass1 accumulates + relu
  int rg = lane >> 4;
  int ncol = nbase + wc * 64 + (lane & 15);
  float bc[4];
#pragma unroll
  for (int ni = 0; ni < 4; ni++) bc[ni] = eb[e * SDIM + ncol + ni * 16];
#pragma unroll
  for (int mi = 0; mi < 4; mi++) {
#pragma unroll
    for (int r = 0; r < 4; r++) {
      int m = wr * 64 + mi * 16 + rg * 4 + r;
      if (m < rows) {
        int tok = gl[m];
        float wgt = wts[tok * 2 + pass];
        float* orow = out + (size_t)tok * SDIM + ncol;
#pragma unroll
        for (int ni = 0; ni < 4; ni++) {
          float v = (acc[mi][ni][r] + bc[ni]) * wgt;
          if (pass) {
            v += orow[ni * 16];
            v = fmaxf(v, 0.f);
          }
          orow[ni * 16] = v;
        }
      }
    }
  }
#undef STAGE
#undef COMPUTE
}

extern "C" void kernel_launch(void* const* d_in, const int* in_sizes, int n_in,
                              void* d_out, int out_size, void* d_ws, size_t ws_size,
                              hipStream_t stream) {
  const float* x        = (const float*)d_in[0];
  const float* gate_w   = (const float*)d_in[1];
  const float* expert_w = (const float*)d_in[2];
  const float* expert_b = (const float*)d_in[3];
  float* out = (float*)d_out;

  char* ws = (char*)d_ws;
  unsigned short* xb = (unsigned short*)(ws);                 // 16,777,216 B
  unsigned short* wb = (unsigned short*)(ws + 16777216);      //  4,194,304 B
  float* wts  = (float*)(ws + 20971520);                      //    131,072 B
  int* sels   = (int*)(ws + 21102592);                        //    131,072 B
  int* cnt    = (int*)(ws + 21233664);                        //         64 B (16 ints)
  int* list0  = (int*)(ws + 21233728);                        //    524,288 B
  int* list1  = (int*)(ws + 21758016);                        //    524,288 B
  int4* desc0 = (int4*)(ws + 22282304);                       //      2,176 B
  int4* desc1 = (int4*)(ws + 22284480);                       //      2,176 B

  hipMemsetAsync(cnt, 0, 64, stream);

  convw_kernel<<<1024, 256, 0, stream>>>(expert_w, wb);
  gate_kernel<<<NT / 4, 256, 0, stream>>>(x, gate_w, xb, out + (size_t)NT * SDIM,
                                          wts, sels);
  scatter_kernel<<<NT / 1024, 1024, 0, stream>>>(sels, cnt, list0, list1);
  build_tiles<<<1, 128, 0, stream>>>(cnt, desc0, desc1);
  dim3 gg(MAX_TP, SDIM / BN);
  moe_gemm<<<gg, 256, 0, stream>>>(xb, wb, list0, wts, desc0, expert_b, out, 0);
  moe_gemm<<<gg, 256, 0, stream>>>(xb, wb, list1, wts, desc1, expert_b, out, 1);
}

// Round 4
// 94.098 us; speedup vs baseline: 5.4235x; 1.2223x over previous
//
#include <hip/hip_runtime.h>
#include <stdint.h>

#define NT 16384   // tokens = 32*512
#define SDIM 512
#define NE 8
#define BM 64
#define BN 128
#define BK 32
#define NPAIR 28
#define MAX_TILES 284   // worst case: 27 one-token buckets + ceil(16357/64) = 283

typedef __attribute__((ext_vector_type(8))) short short8v;
typedef __attribute__((ext_vector_type(8))) unsigned short ushort8v;
typedef __attribute__((ext_vector_type(4))) float f32x4;

#define GLOAD_LDS16(gp, lp) __builtin_amdgcn_global_load_lds( \
    (const __attribute__((address_space(1))) uint32_t*)(gp), \
    (__attribute__((address_space(3))) uint32_t*)(lp), 16, 0, 0)

__device__ __forceinline__ unsigned short f2bf(float f) {
  uint32_t x = __float_as_uint(f);
  x = (x + 0x7FFFu + ((x >> 16) & 1u)) >> 16;
  return (unsigned short)x;
}

// ---------------- expert_w fp32 -> bf16 ----------------
__global__ __launch_bounds__(256) void convw_kernel(const float* __restrict__ w,
                                                    unsigned short* __restrict__ wb) {
  int i = (blockIdx.x * 256 + threadIdx.x) * 8;
  const float4* p = (const float4*)(w + i);
  float4 a = p[0], b = p[1];
  ushort8v u;
  u[0] = f2bf(a.x); u[1] = f2bf(a.y); u[2] = f2bf(a.z); u[3] = f2bf(a.w);
  u[4] = f2bf(b.x); u[5] = f2bf(b.y); u[6] = f2bf(b.z); u[7] = f2bf(b.w);
  *(ushort8v*)(wb + i) = u;
}

// ---------------- gating: fp64 logits, softmax, top-2, x->bf16 ----------------
__global__ __launch_bounds__(256) void gate_kernel(
    const float* __restrict__ x, const float* __restrict__ gw,
    unsigned short* __restrict__ xb, float* __restrict__ gates_out,
    float* __restrict__ wts, int* __restrict__ sels) {
  int lane = threadIdx.x & 63;
  int wv = threadIdx.x >> 6;
  int t = blockIdx.x * 4 + wv;
  const float* xr = x + (size_t)t * SDIM;
  float4 xa = ((const float4*)xr)[lane * 2];
  float4 xbv = ((const float4*)xr)[lane * 2 + 1];

  ushort8v u;
  u[0] = f2bf(xa.x); u[1] = f2bf(xa.y); u[2] = f2bf(xa.z); u[3] = f2bf(xa.w);
  u[4] = f2bf(xbv.x); u[5] = f2bf(xbv.y); u[6] = f2bf(xbv.z); u[7] = f2bf(xbv.w);
  *(ushort8v*)(xb + (size_t)t * SDIM + lane * 8) = u;

  double part[NE];
#pragma unroll
  for (int e = 0; e < NE; e++) {
    const float4* g4 = (const float4*)(gw + e * SDIM + lane * 8);
    float4 ga = g4[0], gb = g4[1];
    double s;
    s  = (double)xa.x * ga.x;  s += (double)xa.y * ga.y;
    s += (double)xa.z * ga.z;  s += (double)xa.w * ga.w;
    s += (double)xbv.x * gb.x; s += (double)xbv.y * gb.y;
    s += (double)xbv.z * gb.z; s += (double)xbv.w * gb.w;
    part[e] = s;
  }
#pragma unroll
  for (int e = 0; e < NE; e++) {
#pragma unroll
    for (int off = 32; off >= 1; off >>= 1)
      part[e] += __shfl_xor(part[e], off, 64);
  }

  float lg[NE];
#pragma unroll
  for (int e = 0; e < NE; e++) lg[e] = (float)part[e];
  float mx = lg[0];
#pragma unroll
  for (int e = 1; e < NE; e++) mx = fmaxf(mx, lg[e]);
  float ex[NE]; float sum = 0.f;
#pragma unroll
  for (int e = 0; e < NE; e++) { ex[e] = expf(lg[e] - mx); sum += ex[e]; }
  float inv = 1.0f / sum;
  float g[NE];
#pragma unroll
  for (int e = 0; e < NE; e++) g[e] = ex[e] * inv;

  // top-2, stable (lower index wins ties) to match jax.lax.top_k
  int s0 = 0; float v0 = g[0];
#pragma unroll
  for (int e = 1; e < NE; e++) if (g[e] > v0) { v0 = g[e]; s0 = e; }
  int s1 = -1; float v1 = -1.0f;
#pragma unroll
  for (int e = 0; e < NE; e++) if (e != s0 && g[e] > v1) { v1 = g[e]; s1 = e; }

  if (lane == 0) {
    float* go = gates_out + (size_t)t * NE;
#pragma unroll
    for (int e = 0; e < NE; e++) go[e] = g[e];
    wts[t * 2] = v0; wts[t * 2 + 1] = v1;
    sels[t * 2] = s0; sels[t * 2 + 1] = s1;
  }
}

// ---------------- block-aggregated scatter into 28 pair-buckets ----------------
__global__ __launch_bounds__(1024) void scatter_kernel(
    const int* __restrict__ sels, int* __restrict__ cnt, int* __restrict__ list) {
  __shared__ int lc[NPAIR];
  __shared__ int lb[NPAIR];
  int tid = threadIdx.x;
  if (tid < NPAIR) lc[tid] = 0;
  __syncthreads();
  int t = blockIdx.x * 1024 + tid;
  int s0 = sels[t * 2], s1 = sels[t * 2 + 1];
  int a = min(s0, s1), b = max(s0, s1);
  int tri = 7 * a - ((a * (a - 1)) >> 1) + (b - a - 1);
  int p = atomicAdd(&lc[tri], 1);
  __syncthreads();
  if (tid < NPAIR) lb[tid] = atomicAdd(cnt + tid, lc[tid]);
  __syncthreads();
  list[tri * NT + lb[tri] + p] = t;
}

// ---------------- tile descriptors over 28 buckets ----------------
__global__ void build_tiles(const int* __restrict__ cnt, int4* __restrict__ desc) {
  if (threadIdx.x == 0 && blockIdx.x == 0) {
    int n = 0, tri = 0;
    for (int a = 0; a < NE; a++) {
      for (int b = a + 1; b < NE; b++, tri++) {
        int c = cnt[tri];
        for (int s = 0; s < c; s += BM)
          desc[n++] = make_int4(a | (b << 8) | (tri << 16), s, min(BM, c - s), 0);
      }
    }
    for (; n < MAX_TILES; n++) desc[n] = make_int4(0, 0, 0, 0);
  }
}

// ---------------- paired grouped GEMM: both experts per token, fused epilogue ----------------
__global__ __launch_bounds__(256, 3) void moe_gemm(
    const unsigned short* __restrict__ xb, const unsigned short* __restrict__ wbuf,
    const int* __restrict__ list, const float* __restrict__ wts,
    const int* __restrict__ sels, const int4* __restrict__ desc,
    const float* __restrict__ ebias, float* __restrict__ out) {
  int4 d = desc[blockIdx.x];
  int rows = d.z;
  if (rows == 0) return;
  int ea = d.x & 255, eb2 = (d.x >> 8) & 255, tri = d.x >> 16;
  int start = d.y;
  int nbase = blockIdx.y * BN;
  const int* gl = list + tri * NT + start;

  __shared__ unsigned short lA[2][BM * BK];           // 2 x 4KB
  __shared__ unsigned short lB[2][2 * BN * BK];       // 2 x 16KB

  int tid = threadIdx.x, lane = tid & 63, wv = tid >> 6;

  // A staging: chunk = tid; row = tid>>2, 16B group (tid&3)
  int ra = tid >> 2;
  int qa = (tid & 3) * 8;
  int trowA = (ra < rows) ? gl[ra] : gl[0];
  const unsigned short* gA = xb + (size_t)trowA * SDIM + qa;

  // B staging: 4 chunks per thread: cb = g*256 + tid; expert slot = cb>>9
  const unsigned short* gB[4];
#pragma unroll
  for (int g = 0; g < 4; g++) {
    int cb = g * 256 + tid;
    int s = cb >> 9;
    int r = (cb >> 2) & (BN - 1);
    int qb = (cb & 3) * 8;
    int e = s ? eb2 : ea;
    gB[g] = wbuf + (size_t)(e * SDIM + nbase + r) * SDIM + qb;
  }

  char* lAb = (char*)lA;
  char* lBb = (char*)lB;
  int wr = wv >> 1, wc = wv & 1;
  int kof = (lane >> 4) * 8;
  int arow = wr * 32 + (lane & 15);
  int brow = wc * 64 + (lane & 15);

  f32x4 acc[2][2][4];
#pragma unroll
  for (int s = 0; s < 2; s++)
#pragma unroll
    for (int i = 0; i < 2; i++)
#pragma unroll
      for (int j = 0; j < 4; j++) acc[s][i][j] = (f32x4){0.f, 0.f, 0.f, 0.f};

#define STAGE(buf, k0) do { \
    GLOAD_LDS16(gA + (k0), lAb + (buf) * 4096 + wv * 1024); \
    _Pragma("unroll") \
    for (int g = 0; g < 4; g++) \
      GLOAD_LDS16(gB[g] + (k0), lBb + (buf) * 16384 + g * 4096 + wv * 1024); \
  } while (0)

#define COMPUTE(buf) do { \
    const unsigned short* pA = lA[buf]; \
    const unsigned short* pB = lB[buf]; \
    short8v a[2], b[2][4]; \
    _Pragma("unroll") \
    for (int mi = 0; mi < 2; mi++) a[mi] = *(const short8v*)&pA[(arow + mi * 16) * BK + kof]; \
    _Pragma("unroll") \
    for (int s = 0; s < 2; s++) \
      _Pragma("unroll") \
      for (int ni = 0; ni < 4; ni++) \
        b[s][ni] = *(const short8v*)&pB[s * (BN * BK) + (brow + ni * 16) * BK + kof]; \
    _Pragma("unroll") \
    for (int s = 0; s < 2; s++) \
      _Pragma("unroll") \
      for (int mi = 0; mi < 2; mi++) \
        _Pragma("unroll") \
        for (int ni = 0; ni < 4; ni++) \
          acc[s][mi][ni] = __builtin_amdgcn_mfma_f32_16x16x32_bf16(a[mi], b[s][ni], acc[s][mi][ni], 0, 0, 0); \
  } while (0)

  STAGE(0, 0);
  __syncthreads();
  int buf = 0;
#pragma unroll 1
  for (int t = 0; t < (SDIM / BK) - 1; t++) {
    STAGE(buf ^ 1, (t + 1) * BK);   // next tile loads in flight during compute
    COMPUTE(buf);
    __syncthreads();
    buf ^= 1;
  }
  COMPUTE(buf);

  // fused epilogue: y = relu(wA*(ya+ba) + wB*(yb+bb)), unique writer per element
  int rg = lane >> 4;
  int ncol = nbase + wc * 64 + (lane & 15);
  float bA[4], bB[4];
#pragma unroll
  for (int ni = 0; ni < 4; ni++) {
    bA[ni] = ebias[ea * SDIM + ncol + ni * 16];
    bB[ni] = ebias[eb2 * SDIM + ncol + ni * 16];
  }
#pragma unroll
  for (int mi = 0; mi < 2; mi++) {
#pragma unroll
    for (int r = 0; r < 4; r++) {
      int m = wr * 32 + mi * 16 + rg * 4 + r;
      if (m < rows) {
        int tok = gl[m];
        float2 wp = *(const float2*)&wts[tok * 2];
        int sA = sels[tok * 2];
        float wA = (sA == ea) ? wp.x : wp.y;
        float wB = (sA == ea) ? wp.y : wp.x;
        float* orow = out + (size_t)tok * SDIM + ncol;
#pragma unroll
        for (int ni = 0; ni < 4; ni++) {
          float v = wA * (acc[0][mi][ni][r] + bA[ni]) + wB * (acc[1][mi][ni][r] + bB[ni]);
          orow[ni * 16] = fmaxf(v, 0.f);
        }
      }
    }
  }
#undef STAGE
#undef COMPUTE
}

extern "C" void kernel_launch(void* const* d_in, const int* in_sizes, int n_in,
                              void* d_out, int out_size, void* d_ws, size_t ws_size,
                              hipStream_t stream) {
  const float* x        = (const float*)d_in[0];
  const float* gate_w   = (const float*)d_in[1];
  const float* expert_w = (const float*)d_in[2];
  const float* expert_b = (const float*)d_in[3];
  float* out = (float*)d_out;

  char* ws = (char*)d_ws;
  unsigned short* xb = (unsigned short*)(ws);                 // 16,777,216 B
  unsigned short* wb = (unsigned short*)(ws + 16777216);      //  4,194,304 B
  float* wts  = (float*)(ws + 20971520);                      //    131,072 B
  int* sels   = (int*)(ws + 21102592);                        //    131,072 B
  int* cnt    = (int*)(ws + 21233664);                        //        128 B
  int* list   = (int*)(ws + 21233792);                        //  1,835,008 B (28*NT*4)
  int4* desc  = (int4*)(ws + 23068800);                       //      4,544 B

  hipMemsetAsync(cnt, 0, 128, stream);

  convw_kernel<<<1024, 256, 0, stream>>>(expert_w, wb);
  gate_kernel<<<NT / 4, 256, 0, stream>>>(x, gate_w, xb, out + (size_t)NT * SDIM,
                                          wts, sels);
  scatter_kernel<<<NT / 1024, 1024, 0, stream>>>(sels, cnt, list);
  build_tiles<<<1, 64, 0, stream>>>(cnt, desc);
  dim3 gg(MAX_TILES, SDIM / BN);
  moe_gemm<<<gg, 256, 0, stream>>>(xb, wb, list, wts, sels, desc, expert_b, out);
}